// Round 7
// baseline (224.320 us; speedup 1.0000x reference)
//
#include <hip/hip_runtime.h>
#include <math.h>

// NT-Xent (SimCLR) loss. B=4096, D=256, T=0.5.
// R7: denom was LDS-PIPE-bound (per-CU: 8 ds_read_b128 x 12cy per wave-phase
// + 16KB/block-phase glds writes ~= 15.5us vs MFMA 8.4us). Split operands
// across pipes: A stays LDS-staged (counted-vmcnt glds, conflict-free b128
// reads), B goes DIRECT from L2 into registers (R2's proven addressing;
// compiler-counted waits; E/O reg ping-pong). LDS demand ~7.8us, VMEM/L2
// ~4-8us, MFMA 8.4us -- three concurrent pipes instead of one at 15.5.
// Also: reduce_kernel FUSED into denom via device-scope ticket: each block
// threadfence+atomicAdd(cnt); the last 32 ticket-holders spin to cnt==NTRI,
// fence-acquire, and each reduces a 256-row slice (saves a launch + gap).
//   zbF layout: rg = row>>4, ks = k>>5:
//     offset_shorts = rg*4096 + ks*512 + ((k>>3)&3)*128 + (row&15)*8 + (k&7)
// Rows scaled by sqrt(2/ln2): acc = 2*sim/ln2 -> epilogue exp2(acc);
// posv holds 2*sim/ln2; fused reduce weight = 2*ln2.

#define NROWS 8192
#define NHALF 4096
#define DIM   256
#define BM    128
#define BN    128
#define NCB   (NROWS / BN)          // 64 row/col blocks
#define NTRI  (NCB * (NCB + 1) / 2) // 2080 triangle tiles
#define NRED  32                    // reducer blocks (last 32 tickets)

typedef __attribute__((ext_vector_type(8))) short bf16x8;
typedef __attribute__((ext_vector_type(4))) float f32x4;

static __device__ __forceinline__ unsigned short f2bf(float x) {
  unsigned int u = __float_as_uint(x);
  unsigned int r = (u + 0x7FFFu + ((u >> 16) & 1u)) >> 16;
  return (unsigned short)r;
}

// ---------------- normalize -> fragment-native layout; zero out[0], cnt
__global__ __launch_bounds__(256) void normalize_kernel(
    const float* __restrict__ emb_i, const float* __restrict__ emb_j,
    unsigned short* __restrict__ zbF, float* __restrict__ out,
    unsigned int* __restrict__ cnt) {
  __shared__ unsigned short tile[16 * DIM];  // 8 KB
  if (blockIdx.x == 0 && threadIdx.x == 0) {
    out[0] = 0.f;
    *cnt = 0u;
  }
  const int w = threadIdx.x >> 6, lane = threadIdx.x & 63;
  const int rg = blockIdx.x;
  #pragma unroll
  for (int rr = 0; rr < 4; ++rr) {
    const int m16 = w * 4 + rr;
    const int row = rg * 16 + m16;
    const float* src = (row < NHALF) ? (emb_i + (size_t)row * DIM)
                                     : (emb_j + (size_t)(row - NHALF) * DIM);
    float4 v = ((const float4*)src)[lane];
    float ss = v.x * v.x + v.y * v.y + v.z * v.z + v.w * v.w;
    #pragma unroll
    for (int off = 32; off; off >>= 1) ss += __shfl_down(ss, off, 64);
    float total = __shfl(ss, 0, 64);
    // sqrt(2/ln2): acc = 2*sim/ln2, so epilogue is exp2(acc) directly.
    float inv = 1.69870077f / fmaxf(sqrtf(total), 1e-12f);
    ushort4 o;
    o.x = f2bf(v.x * inv); o.y = f2bf(v.y * inv);
    o.z = f2bf(v.z * inv); o.w = f2bf(v.w * inv);
    // k = lane*4 -> ks = lane>>3, quad = (lane>>1)&3, j = (lane&1)*4
    const int ks = lane >> 3, quad = (lane >> 1) & 3, jj = (lane & 1) * 4;
    *(ushort4*)&tile[ks * 512 + (quad * 16 + m16) * 8 + jj] = o;
  }
  __syncthreads();
  uint4* dst = (uint4*)(zbF + (size_t)rg * (16 * DIM));
  const uint4* srcT = (const uint4*)tile;
  dst[threadIdx.x] = srcT[threadIdx.x];
  dst[256 + threadIdx.x] = srcT[256 + threadIdx.x];
}

// ---------------- MFMA GEMM + exp + sums + fused tail reduce
__global__ __launch_bounds__(256, 4) void denom_kernel(
    const unsigned short* __restrict__ zbF, float* __restrict__ denomP,
    float* __restrict__ posv, float* __restrict__ out,
    unsigned int* __restrict__ cnt) {
  __shared__ unsigned short As[2][8 * 512];  // 2 x 8 KB (one K=32 A-slice)
  __shared__ float red[512];                 // 2 KB reduction buffer
  __shared__ int tk;

  // XCD-aware bijective swizzle (2080 % 8 == 0)
  int t = (blockIdx.x & 7) * (NTRI / 8) + (blockIdx.x >> 3);
  int by = (int)((sqrtf(8.0f * (float)t + 1.0f) - 1.0f) * 0.5f);
  while ((by + 1) * (by + 2) / 2 <= t) ++by;
  while (by * (by + 1) / 2 > t) --by;
  int bx = t - by * (by + 1) / 2;

  const int tid = threadIdx.x;
  const int w = tid >> 6;
  const int lane = tid & 63;
  const int wr = w >> 1, wc = w & 1;  // 2x2 wave grid, 64x64 each
  const int quad = lane >> 4;
  const int m16 = lane & 15;
  const int row0 = bx * BM;
  const int col0 = by * BN;

  // A staging: per-lane 16 B within each 1 KB chunk; wave w stages chunks
  // {w, w+4} of the 8 per K=32 slice. Linear LDS dest == frag layout.
  const unsigned short* gA = zbF + (size_t)(bx * 8) * 4096 + lane * 8;
  // B direct: frag j of slice ks at gB + j*4096 + ks*512 (per-lane +lane*8).
  const unsigned short* gB =
      zbF + (size_t)(by * 8 + wc * 4) * 4096 + lane * 8;

  f32x4 acc[4][4];
  #pragma unroll
  for (int i = 0; i < 4; ++i)
    #pragma unroll
    for (int j = 0; j < 4; ++j) {
      f32x4 z4 = {0.f, 0.f, 0.f, 0.f};
      acc[i][j] = z4;
    }

  auto stageA = [&](int b, int ks) {
    #pragma unroll
    for (int r = 0; r < 2; ++r) {
      const int c = r * 4 + w;
      __builtin_amdgcn_global_load_lds(
          (const __attribute__((address_space(1))) unsigned int*)(gA +
              (size_t)c * 4096 + ks * 512),
          (__attribute__((address_space(3))) unsigned int*)&As[b][c * 512],
          16, 0, 0);
    }
  };

#define LOADB(BREG, ks)                                                    \
  do {                                                                     \
    _Pragma("unroll") for (int j = 0; j < 4; ++j)                          \
        BREG[j] = *(const bf16x8*)(gB + (size_t)j * 4096 + (ks) * 512);    \
  } while (0)

  // compute: A-frag loaded per-i (keeps only ~1-2 frags live -> low VGPR)
#define COMPUTE(BUF, BREG)                                                 \
  do {                                                                     \
    _Pragma("unroll") for (int i = 0; i < 4; ++i) {                        \
      bf16x8 af = *(const bf16x8*)&As[BUF][(wr * 4 + i) * 512 + lane * 8]; \
      __builtin_amdgcn_s_setprio(1);                                       \
      _Pragma("unroll") for (int j = 0; j < 4; ++j)                        \
          acc[i][j] = __builtin_amdgcn_mfma_f32_16x16x32_bf16(             \
              af, BREG[j], acc[i][j], 0, 0, 0);                            \
      __builtin_amdgcn_s_setprio(0);                                       \
    }                                                                      \
  } while (0)

  bf16x8 bE[4], bO[4];
  // prologue: slice 0 (6 VMEM ops: 2 glds + 4 B-loads)
  stageA(0, 0);
  LOADB(bE, 0);

  // PHASE ks: issue ks+1's 6 VMEM ops; vmcnt(6) retires ks's 6; barrier
  // (A(ks) visible); compute; trailing barrier (WAR before next stage).
#define PHASE_PRE(ksp1, BUFN, BREGN)                                       \
  do {                                                                     \
    stageA(BUFN, ksp1);                                                    \
    LOADB(BREGN, ksp1);                                                    \
    asm volatile("s_waitcnt vmcnt(6)" ::: "memory");                       \
  } while (0)
#define PHASE_BODY(BUF, BREG)                                              \
  do {                                                                     \
    __builtin_amdgcn_s_barrier();                                          \
    asm volatile("" ::: "memory");                                         \
    COMPUTE(BUF, BREG);                                                    \
    asm volatile("" ::: "memory");                                         \
    __builtin_amdgcn_s_barrier();                                          \
    asm volatile("" ::: "memory");                                         \
  } while (0)

  PHASE_PRE(1, 1, bO); PHASE_BODY(0, bE);  // ks=0
  PHASE_PRE(2, 0, bE); PHASE_BODY(1, bO);  // ks=1
  PHASE_PRE(3, 1, bO); PHASE_BODY(0, bE);  // ks=2
  PHASE_PRE(4, 0, bE); PHASE_BODY(1, bO);  // ks=3
  PHASE_PRE(5, 1, bO); PHASE_BODY(0, bE);  // ks=4
  PHASE_PRE(6, 0, bE); PHASE_BODY(1, bO);  // ks=5
  PHASE_PRE(7, 1, bO); PHASE_BODY(0, bE);  // ks=6
  asm volatile("s_waitcnt vmcnt(0)" ::: "memory");  // ks=7: drain last
  __builtin_amdgcn_s_barrier();
  asm volatile("" ::: "memory");
  COMPUTE(1, bO);
#undef PHASE_PRE
#undef PHASE_BODY
#undef COMPUTE
#undef LOADB

  // pos extraction: only tiles with col0 == row0 + NHALF hold pair elements.
  if (col0 - row0 == NHALF) {
    #pragma unroll
    for (int i = 0; i < 4; ++i)
      #pragma unroll
      for (int j = 0; j < 4; ++j) {
        int gcol = col0 + wc * 64 + j * 16 + m16;
        #pragma unroll
        for (int r = 0; r < 4; ++r) {
          int grow = row0 + wr * 64 + i * 16 + quad * 4 + r;
          if (gcol - grow == NHALF) posv[grow] = acc[i][j][r];
        }
      }
  }

  // Epilogue: e = exp2(acc) = exp(2*sim). Diagonal tiles (bx==by) pay the
  // grow==gcol compare; off-diagonal tiles skip it.
  float rs[4][4];
  float cs[4] = {0.f, 0.f, 0.f, 0.f};
  #pragma unroll
  for (int i = 0; i < 4; ++i)
    #pragma unroll
    for (int r = 0; r < 4; ++r) rs[i][r] = 0.f;

  if (bx != by) {
    #pragma unroll
    for (int i = 0; i < 4; ++i)
      #pragma unroll
      for (int j = 0; j < 4; ++j)
        #pragma unroll
        for (int r = 0; r < 4; ++r) {
          float e = __builtin_amdgcn_exp2f(acc[i][j][r]);
          rs[i][r] += e;
          cs[j] += e;
        }
  } else {
    #pragma unroll
    for (int i = 0; i < 4; ++i)
      #pragma unroll
      for (int j = 0; j < 4; ++j) {
        int gcol = col0 + wc * 64 + j * 16 + m16;
        #pragma unroll
        for (int r = 0; r < 4; ++r) {
          int grow = row0 + wr * 64 + i * 16 + quad * 4 + r;
          float e =
              (grow == gcol) ? 0.f : __builtin_amdgcn_exp2f(acc[i][j][r]);
          rs[i][r] += e;
          cs[j] += e;
        }
      }
  }

  // rowsum: reduce across the 16 column lanes (same quad)
  #pragma unroll
  for (int i = 0; i < 4; ++i)
    #pragma unroll
    for (int r = 0; r < 4; ++r) {
      float v = rs[i][r];
      v += __shfl_xor(v, 1, 16);
      v += __shfl_xor(v, 2, 16);
      v += __shfl_xor(v, 4, 16);
      v += __shfl_xor(v, 8, 16);
      if (m16 == 0) red[wc * 128 + wr * 64 + i * 16 + quad * 4 + r] = v;
    }
  // colsum: reduce across the 4 quads
  #pragma unroll
  for (int j = 0; j < 4; ++j) {
    float v = cs[j];
    v += __shfl_xor(v, 16, 64);
    v += __shfl_xor(v, 32, 64);
    if (quad == 0) red[256 + wr * 128 + wc * 64 + j * 16 + m16] = v;
  }
  __syncthreads();

  if (tid < 128) {
    denomP[(size_t)by * NROWS + row0 + tid] = red[tid] + red[128 + tid];
  } else if (bx != by) {
    int c = tid - 128;
    denomP[(size_t)bx * NROWS + col0 + c] = red[256 + c] + red[384 + c];
  }

  // ---- fused tail reduce: ticket; last NRED blocks do 256 rows each ----
  __threadfence();   // release this block's denomP/posv writes (all threads)
  __syncthreads();
  if (tid == 0) tk = (int)atomicAdd(cnt, 1u);
  __syncthreads();
  if (tk < NTRI - NRED) return;

  if (tid == 0) {
    while (atomicAdd(cnt, 0u) < (unsigned)NTRI) __builtin_amdgcn_s_sleep(8);
  }
  __syncthreads();
  __threadfence();  // acquire: all tiles' denomP/posv now visible

  const int r = (tk - (NTRI - NRED)) * 256 + tid;
  float s = 0.f;
  #pragma unroll 8
  for (int b = 0; b < NCB; ++b) s += denomP[(size_t)b * NROWS + r];
  float v = -logf(s);
  // posv = 2*sim/ln2; need 4*sim (rows r and r+NHALF) = 2*ln2*posv
  if (r < NHALF) v += 1.38629436112f * posv[r];
  #pragma unroll
  for (int off = 32; off; off >>= 1) v += __shfl_down(v, off, 64);
  __syncthreads();  // red[] reuse safe (prior readers done)
  if ((tid & 63) == 0) red[tid >> 6] = v;
  __syncthreads();
  if (tid == 0)
    atomicAdd(out, (red[0] + red[1] + red[2] + red[3]) * (1.0f / 8192.0f));
}

extern "C" void kernel_launch(void* const* d_in, const int* in_sizes, int n_in,
                              void* d_out, int out_size, void* d_ws,
                              size_t ws_size, hipStream_t stream) {
  const float* emb_i = (const float*)d_in[0];
  const float* emb_j = (const float*)d_in[1];
  unsigned short* zbF = (unsigned short*)d_ws;           // 4 MB (frag layout)
  float* denomP = (float*)(zbF + (size_t)NROWS * DIM);   // 64*8192 f32 (2 MB)
  float* posv = denomP + (size_t)NCB * NROWS;            // 4096 f32
  unsigned int* cnt = (unsigned int*)(posv + NHALF);     // 1 u32 ticket
  float* out = (float*)d_out;

  normalize_kernel<<<NROWS / 16, 256, 0, stream>>>(emb_i, emb_j, zbF, out,
                                                   cnt);
  denom_kernel<<<NTRI, 256, 0, stream>>>(zbF, denomP, posv, out, cnt);
}

// Round 8
// 94.755 us; speedup vs baseline: 2.3674x; 2.3674x over previous
//
#include <hip/hip_runtime.h>
#include <math.h>

// NT-Xent (SimCLR) loss. B=4096, D=256, T=0.5.
// R8: R7's pipe-split GEMM (verified correct: A LDS-staged via counted-vmcnt
// glds + B direct-from-L2 into regs) WITHOUT R7's fused tail. R7 post-mortem:
// in-kernel cross-block handoff needs device-scope release; on CDNA4 (non-
// coherent per-XCD L2) __threadfence() = L2 writeback -- paid 2080x, +140us.
// The kernel boundary is the cheap fence: back to 3 kernels.
// GEMM pipe budget/CU: LDS ~7.8us (4 ds_read_b128/wave-phase + 8KB writes),
// VMEM/L2 ~4-7us (B, L1-deduped), MFMA 8.4us -- three concurrent ~8us pipes.
//   zbF layout: rg = row>>4, ks = k>>5:
//     offset_shorts = rg*4096 + ks*512 + ((k>>3)&3)*128 + (row&15)*8 + (k&7)
// Rows scaled by sqrt(2/ln2): acc = 2*sim/ln2 -> epilogue exp2(acc);
// posv holds 2*sim/ln2; reduce weight = 2*ln2.

#define NROWS 8192
#define NHALF 4096
#define DIM   256
#define BM    128
#define BN    128
#define NCB   (NROWS / BN)          // 64 row/col blocks
#define NTRI  (NCB * (NCB + 1) / 2) // 2080 triangle tiles

typedef __attribute__((ext_vector_type(8))) short bf16x8;
typedef __attribute__((ext_vector_type(4))) float f32x4;

static __device__ __forceinline__ unsigned short f2bf(float x) {
  unsigned int u = __float_as_uint(x);
  unsigned int r = (u + 0x7FFFu + ((u >> 16) & 1u)) >> 16;
  return (unsigned short)r;
}

// ---------------- normalize -> fragment-native layout (also zeroes out[0])
__global__ __launch_bounds__(256) void normalize_kernel(
    const float* __restrict__ emb_i, const float* __restrict__ emb_j,
    unsigned short* __restrict__ zbF, float* __restrict__ out) {
  __shared__ unsigned short tile[16 * DIM];  // 8 KB
  if (blockIdx.x == 0 && threadIdx.x == 0) out[0] = 0.f;
  const int w = threadIdx.x >> 6, lane = threadIdx.x & 63;
  const int rg = blockIdx.x;
  #pragma unroll
  for (int rr = 0; rr < 4; ++rr) {
    const int m16 = w * 4 + rr;
    const int row = rg * 16 + m16;
    const float* src = (row < NHALF) ? (emb_i + (size_t)row * DIM)
                                     : (emb_j + (size_t)(row - NHALF) * DIM);
    float4 v = ((const float4*)src)[lane];
    float ss = v.x * v.x + v.y * v.y + v.z * v.z + v.w * v.w;
    #pragma unroll
    for (int off = 32; off; off >>= 1) ss += __shfl_down(ss, off, 64);
    float total = __shfl(ss, 0, 64);
    // sqrt(2/ln2): acc = 2*sim/ln2, so epilogue is exp2(acc) directly.
    float inv = 1.69870077f / fmaxf(sqrtf(total), 1e-12f);
    ushort4 o;
    o.x = f2bf(v.x * inv); o.y = f2bf(v.y * inv);
    o.z = f2bf(v.z * inv); o.w = f2bf(v.w * inv);
    // k = lane*4 -> ks = lane>>3, quad = (lane>>1)&3, j = (lane&1)*4
    const int ks = lane >> 3, quad = (lane >> 1) & 3, jj = (lane & 1) * 4;
    *(ushort4*)&tile[ks * 512 + (quad * 16 + m16) * 8 + jj] = o;
  }
  __syncthreads();
  uint4* dst = (uint4*)(zbF + (size_t)rg * (16 * DIM));
  const uint4* srcT = (const uint4*)tile;
  dst[threadIdx.x] = srcT[threadIdx.x];
  dst[256 + threadIdx.x] = srcT[256 + threadIdx.x];
}

// ------------------------------------------------ MFMA GEMM + exp + sums
__global__ __launch_bounds__(256, 4) void denom_kernel(
    const unsigned short* __restrict__ zbF, float* __restrict__ denomP,
    float* __restrict__ posv) {
  __shared__ unsigned short As[2][8 * 512];  // 2 x 8 KB (one K=32 A-slice)
  __shared__ float red[512];                 // 2 KB reduction buffer

  // XCD-aware bijective swizzle (2080 % 8 == 0)
  int t = (blockIdx.x & 7) * (NTRI / 8) + (blockIdx.x >> 3);
  int by = (int)((sqrtf(8.0f * (float)t + 1.0f) - 1.0f) * 0.5f);
  while ((by + 1) * (by + 2) / 2 <= t) ++by;
  while (by * (by + 1) / 2 > t) --by;
  int bx = t - by * (by + 1) / 2;

  const int tid = threadIdx.x;
  const int w = tid >> 6;
  const int lane = tid & 63;
  const int wr = w >> 1, wc = w & 1;  // 2x2 wave grid, 64x64 each
  const int quad = lane >> 4;
  const int m16 = lane & 15;
  const int row0 = bx * BM;
  const int col0 = by * BN;

  // A staging: per-lane 16 B within each 1 KB chunk; wave w stages chunks
  // {w, w+4} of the 8 per K=32 slice. Linear LDS dest == frag layout.
  const unsigned short* gA = zbF + (size_t)(bx * 8) * 4096 + lane * 8;
  // B direct: frag j of slice ks at gB + j*4096 + ks*512 (per-lane +lane*8).
  const unsigned short* gB =
      zbF + (size_t)(by * 8 + wc * 4) * 4096 + lane * 8;

  f32x4 acc[4][4];
  #pragma unroll
  for (int i = 0; i < 4; ++i)
    #pragma unroll
    for (int j = 0; j < 4; ++j) {
      f32x4 z4 = {0.f, 0.f, 0.f, 0.f};
      acc[i][j] = z4;
    }

  auto stageA = [&](int b, int ks) {
    #pragma unroll
    for (int r = 0; r < 2; ++r) {
      const int c = r * 4 + w;
      __builtin_amdgcn_global_load_lds(
          (const __attribute__((address_space(1))) unsigned int*)(gA +
              (size_t)c * 4096 + ks * 512),
          (__attribute__((address_space(3))) unsigned int*)&As[b][c * 512],
          16, 0, 0);
    }
  };

#define LOADB(BREG, ks)                                                    \
  do {                                                                     \
    _Pragma("unroll") for (int j = 0; j < 4; ++j)                          \
        BREG[j] = *(const bf16x8*)(gB + (size_t)j * 4096 + (ks) * 512);    \
  } while (0)

  // compute: A-frag loaded per-i (keeps only ~1-2 frags live -> low VGPR)
#define COMPUTE(BUF, BREG)                                                 \
  do {                                                                     \
    _Pragma("unroll") for (int i = 0; i < 4; ++i) {                        \
      bf16x8 af = *(const bf16x8*)&As[BUF][(wr * 4 + i) * 512 + lane * 8]; \
      __builtin_amdgcn_s_setprio(1);                                       \
      _Pragma("unroll") for (int j = 0; j < 4; ++j)                        \
          acc[i][j] = __builtin_amdgcn_mfma_f32_16x16x32_bf16(             \
              af, BREG[j], acc[i][j], 0, 0, 0);                            \
      __builtin_amdgcn_s_setprio(0);                                       \
    }                                                                      \
  } while (0)

  bf16x8 bE[4], bO[4];
  // prologue: slice 0 (6 VMEM ops: 2 glds + 4 B-loads)
  stageA(0, 0);
  LOADB(bE, 0);

  // PHASE ks: issue ks+1's 6 VMEM ops; vmcnt(6) retires ks's 6; barrier
  // (A(ks) visible); compute; trailing barrier (WAR before next stage).
#define PHASE_PRE(ksp1, BUFN, BREGN)                                       \
  do {                                                                     \
    stageA(BUFN, ksp1);                                                    \
    LOADB(BREGN, ksp1);                                                    \
    asm volatile("s_waitcnt vmcnt(6)" ::: "memory");                       \
  } while (0)
#define PHASE_BODY(BUF, BREG)                                              \
  do {                                                                     \
    __builtin_amdgcn_s_barrier();                                          \
    asm volatile("" ::: "memory");                                         \
    COMPUTE(BUF, BREG);                                                    \
    asm volatile("" ::: "memory");                                         \
    __builtin_amdgcn_s_barrier();                                          \
    asm volatile("" ::: "memory");                                         \
  } while (0)

  PHASE_PRE(1, 1, bO); PHASE_BODY(0, bE);  // ks=0
  PHASE_PRE(2, 0, bE); PHASE_BODY(1, bO);  // ks=1
  PHASE_PRE(3, 1, bO); PHASE_BODY(0, bE);  // ks=2
  PHASE_PRE(4, 0, bE); PHASE_BODY(1, bO);  // ks=3
  PHASE_PRE(5, 1, bO); PHASE_BODY(0, bE);  // ks=4
  PHASE_PRE(6, 0, bE); PHASE_BODY(1, bO);  // ks=5
  PHASE_PRE(7, 1, bO); PHASE_BODY(0, bE);  // ks=6
  asm volatile("s_waitcnt vmcnt(0)" ::: "memory");  // ks=7: drain last
  __builtin_amdgcn_s_barrier();
  asm volatile("" ::: "memory");
  COMPUTE(1, bO);
#undef PHASE_PRE
#undef PHASE_BODY
#undef COMPUTE
#undef LOADB

  // pos extraction: only tiles with col0 == row0 + NHALF hold pair elements.
  if (col0 - row0 == NHALF) {
    #pragma unroll
    for (int i = 0; i < 4; ++i)
      #pragma unroll
      for (int j = 0; j < 4; ++j) {
        int gcol = col0 + wc * 64 + j * 16 + m16;
        #pragma unroll
        for (int r = 0; r < 4; ++r) {
          int grow = row0 + wr * 64 + i * 16 + quad * 4 + r;
          if (gcol - grow == NHALF) posv[grow] = acc[i][j][r];
        }
      }
  }

  // Epilogue: e = exp2(acc) = exp(2*sim). Diagonal tiles (bx==by) pay the
  // grow==gcol compare; off-diagonal tiles skip it.
  float rs[4][4];
  float cs[4] = {0.f, 0.f, 0.f, 0.f};
  #pragma unroll
  for (int i = 0; i < 4; ++i)
    #pragma unroll
    for (int r = 0; r < 4; ++r) rs[i][r] = 0.f;

  if (bx != by) {
    #pragma unroll
    for (int i = 0; i < 4; ++i)
      #pragma unroll
      for (int j = 0; j < 4; ++j)
        #pragma unroll
        for (int r = 0; r < 4; ++r) {
          float e = __builtin_amdgcn_exp2f(acc[i][j][r]);
          rs[i][r] += e;
          cs[j] += e;
        }
  } else {
    #pragma unroll
    for (int i = 0; i < 4; ++i)
      #pragma unroll
      for (int j = 0; j < 4; ++j) {
        int gcol = col0 + wc * 64 + j * 16 + m16;
        #pragma unroll
        for (int r = 0; r < 4; ++r) {
          int grow = row0 + wr * 64 + i * 16 + quad * 4 + r;
          float e =
              (grow == gcol) ? 0.f : __builtin_amdgcn_exp2f(acc[i][j][r]);
          rs[i][r] += e;
          cs[j] += e;
        }
      }
  }

  // rowsum: reduce across the 16 column lanes (same quad)
  #pragma unroll
  for (int i = 0; i < 4; ++i)
    #pragma unroll
    for (int r = 0; r < 4; ++r) {
      float v = rs[i][r];
      v += __shfl_xor(v, 1, 16);
      v += __shfl_xor(v, 2, 16);
      v += __shfl_xor(v, 4, 16);
      v += __shfl_xor(v, 8, 16);
      if (m16 == 0) red[wc * 128 + wr * 64 + i * 16 + quad * 4 + r] = v;
    }
  // colsum: reduce across the 4 quads
  #pragma unroll
  for (int j = 0; j < 4; ++j) {
    float v = cs[j];
    v += __shfl_xor(v, 16, 64);
    v += __shfl_xor(v, 32, 64);
    if (quad == 0) red[256 + wr * 128 + wc * 64 + j * 16 + m16] = v;
  }
  __syncthreads();

  if (tid < 128) {
    denomP[(size_t)by * NROWS + row0 + tid] = red[tid] + red[128 + tid];
  } else if (bx != by) {
    int c = tid - 128;
    denomP[(size_t)bx * NROWS + col0 + c] = red[256 + c] + red[384 + c];
  }
}

// -------------------- denom slots -> -log; + 2*ln2*pos'; atomic into loss
__global__ __launch_bounds__(256) void reduce_kernel(
    const float* __restrict__ denomP, const float* __restrict__ posv,
    float* __restrict__ out) {
  int tid = threadIdx.x;
  int r = blockIdx.x * 256 + tid;  // 32 blocks cover 8192 rows
  float s = 0.f;
  #pragma unroll 8
  for (int b = 0; b < NCB; ++b) s += denomP[(size_t)b * NROWS + r];
  float v = -logf(s);
  // posv = 2*sim/ln2; need 4*sim (rows r and r+NHALF) = 2*ln2*posv
  if (r < NHALF) v += 1.38629436112f * posv[r];
  #pragma unroll
  for (int off = 32; off; off >>= 1) v += __shfl_down(v, off, 64);
  __shared__ float s4[4];
  if ((tid & 63) == 0) s4[tid >> 6] = v;
  __syncthreads();
  if (tid == 0)
    atomicAdd(out, (s4[0] + s4[1] + s4[2] + s4[3]) * (1.0f / 8192.0f));
}

extern "C" void kernel_launch(void* const* d_in, const int* in_sizes, int n_in,
                              void* d_out, int out_size, void* d_ws,
                              size_t ws_size, hipStream_t stream) {
  const float* emb_i = (const float*)d_in[0];
  const float* emb_j = (const float*)d_in[1];
  unsigned short* zbF = (unsigned short*)d_ws;           // 4 MB (frag layout)
  float* denomP = (float*)(zbF + (size_t)NROWS * DIM);   // 64*8192 f32 (2 MB)
  float* posv = denomP + (size_t)NCB * NROWS;            // 4096 f32
  float* out = (float*)d_out;

  normalize_kernel<<<NROWS / 16, 256, 0, stream>>>(emb_i, emb_j, zbF, out);
  denom_kernel<<<NTRI, 256, 0, stream>>>(zbF, denomP, posv);
  reduce_kernel<<<NROWS / 256, 256, 0, stream>>>(denomP, posv, out);
}